// Round 10
// baseline (4248.723 us; speedup 1.0000x reference)
//
#include <hip/hip_runtime.h>

#define T_LEN 1024
#define B_SZ  256
#define D_DIM 64
#define E_DIM 512
#define H_DIM 256

#define SA 552   // flow A-tile LDS stride (bf16 elems) — 2-way max (verified)
#define SH 264   // flow hid-tile LDS stride — 2-way max
#define SF 66    // flow stf stride (floats) — 2-way max
#define ROWB 1152  // esn LDS row stride BYTES (576 fp16)

#define ESN_LDS  (80 * ROWB)                                        // 92160
#define FLOW_LDS (32*SA*2 + 32*SH*2 + 32*64*4 + 32*4 + 16*4)        // 60608

using short8 = __attribute__((ext_vector_type(8))) short;
using half8  = __attribute__((ext_vector_type(8))) _Float16;
using f32x4  = __attribute__((ext_vector_type(4))) float;
typedef unsigned long long ull;

static __device__ __forceinline__ unsigned short f2bf(float v) {
    unsigned u = __float_as_uint(v);
    u += 0x7FFFu + ((u >> 16) & 1u);   // RNE to bf16
    return (unsigned short)(u >> 16);
}
static __device__ __forceinline__ unsigned short f2h(float v) {
    _Float16 h = (_Float16)v;
    unsigned short u;
    __builtin_memcpy(&u, &h, 2);
    return u;
}
static __device__ __forceinline__ float h2f(unsigned short u) {
    _Float16 h;
    __builtin_memcpy(&h, &u, 2);
    return (float)h;
}
static __device__ __forceinline__ float fast_tanh(float x) {
    x = fminf(15.f, fmaxf(-15.f, x));
    float e = __expf(2.f * x);
    return (e - 1.f) / (e + 1.f);
}
// XOR bank swizzle within each 128B sub-block of a 1152B row (both-sides involution).
static __device__ __forceinline__ int rswz(int row, int byte_in_row) {
    return row * ROWB + (byte_in_row ^ ((row & 7) << 4));
}

// ---- Weight prep (R9, verified) ----
__global__ void prep_kernel(const float* __restrict__ W_in, const float* __restrict__ W_s,
                            const float* __restrict__ W_t, const float* __restrict__ W_res,
                            const float* __restrict__ W_inp, const float* __restrict__ x_seq,
                            unsigned short* __restrict__ W_inF, unsigned short* __restrict__ W_stF,
                            unsigned short* __restrict__ W_packo, unsigned short* __restrict__ x_h) {
    int idx = blockIdx.x * blockDim.x + threadIdx.x;
    int stride = gridDim.x * blockDim.x;
    const int total1 = 8 * 16 * 17 * 64 * 8;        // W_inF
    for (int i = idx; i < total1; i += stride) {
        int j    = i & 7;
        int lane = (i >> 3) & 63;
        int ks   = (i >> 9) % 17;
        int nt   = (i / (512 * 17)) & 15;
        int ls   = i / (512 * 17 * 16);
        int side = ls & 1, l = ls >> 1;
        int n = nt * 16 + (lane & 15);
        int k = ks * 32 + (lane >> 4) * 8 + j;
        int ksrc = (k < 32) ? (side == 0 ? 32 + k : k) : (k + 32);
        W_inF[i] = f2bf(W_in[(l * 576 + ksrc) * H_DIM + n]);
    }
    const int total2 = 8 * 4 * 8 * 64 * 8;          // W_stF
    for (int i = idx; i < total2; i += stride) {
        int j    = i & 7;
        int lane = (i >> 3) & 63;
        int ks   = (i >> 9) & 7;
        int nt   = (i >> 12) & 3;
        int ls   = i >> 14;
        int side = ls & 1, l = ls >> 1;
        int nst = nt * 16 + (lane & 15);
        int k   = ks * 32 + (lane >> 4) * 8 + j;
        int j32 = nst & 31;
        int d   = side ? (32 + j32) : j32;
        float v = (nst < 32) ? W_s[(l * H_DIM + k) * D_DIM + d] : W_t[(l * H_DIM + k) * D_DIM + d];
        W_stF[i] = f2bf(v);
    }
    const int total3 = E_DIM * 576;
    for (int i = idx; i < total3; i += stride) {
        int k = i % 576;
        int n = i / 576;
        float v = (k < E_DIM) ? W_res[n * E_DIM + k] : W_inp[(k - E_DIM) * E_DIM + n];
        W_packo[i] = f2h(v);
    }
    const int total4 = T_LEN * B_SZ * D_DIM;
    for (int i = idx; i < total4; i += stride)
        x_h[i] = f2h(x_seq[i]);
}

// ---- Fused pipelined kernel ----
// If tce>0: blocks [0,128) run the ESN chain for chunk [t0e, t0e+tce) writing hse.
// Blocks [ebn, ebn+tcf) run flow for chunk [t0f, t0f+tcf) reading hsf.
// hse != hsf (double buffer); launch ordering guarantees hsf is complete.
__launch_bounds__(256, 1)
__global__ void fused_kernel(const unsigned short* __restrict__ x_h,
                             const unsigned short* __restrict__ W_pack,
                             unsigned short* __restrict__ hse /*bf16 [tce][B][E]*/,
                             unsigned short* __restrict__ h_buf /*fp16 [2][B][E]*/,
                             unsigned int* __restrict__ ctr,
                             int t0e, int tce,
                             const float* __restrict__ x_seq,
                             const unsigned short* __restrict__ hsf /*bf16 [tcf][B][E]*/,
                             const unsigned short* __restrict__ W_inF,
                             const unsigned short* __restrict__ W_stF,
                             const float* __restrict__ b_in, const float* __restrict__ b_s,
                             const float* __restrict__ b_t, const float* __restrict__ rescale_w,
                             const int* __restrict__ seq_len, float* __restrict__ ll_part,
                             int t0f, int tcf) {
    extern __shared__ char smem[];
    const int ebn = (tce > 0) ? 128 : 0;
    const int tid = threadIdx.x;
    const int wave = tid >> 6;
    const int lane = tid & 63;

    if ((int)blockIdx.x < ebn) {
        // ================= ESN part (R8/R9 verified structure) =================
        const int bid  = blockIdx.x;
        const int g    = bid & 15;
        const int m    = bid >> 4;
        const int arow = lane & 15;
        const int kq   = lane >> 4;
        const int r0   = g * 16;
        const int n0   = m * 64;
        const size_t HB = (size_t)B_SZ * E_DIM;
        unsigned int* gctr = ctr + g * 32;

        char* Wlb = smem;                 // [64][1152B] W-slice, swizzled
        char* hAb = smem + 64 * ROWB;     // [16][1152B] = [h(1024B) | x(128B)], swizzled

        {   // W-slice -> LDS (swizzled write; one-time)
            const int r  = tid & 63;
            const int c0 = (tid >> 6) * 18;
            #pragma unroll
            for (int u = 0; u < 18; ++u) {
                const int byte = 16 * (c0 + u);
                *reinterpret_cast<uint4*>(Wlb + rswz(r, byte)) =
                    *reinterpret_cast<const uint4*>(
                        reinterpret_cast<const char*>(&W_pack[(size_t)(n0 + r) * 576]) + byte);
            }
        }

        const int srow = tid >> 4;
        const int seg  = tid & 15;
        const int xrow = tid >> 2, xc = tid & 3;

        for (int tl = 0; tl < tce; ++tl) {
            const int t = t0e + tl;
            const unsigned short* hb_r = h_buf + (size_t)(t & 1) * HB;
            unsigned short*       hb_w = h_buf + (size_t)((t & 1) ^ 1) * HB;

            uint4 xa = {0,0,0,0}, xb = {0,0,0,0};
            if (tid < 64) {
                const unsigned short* xp = &x_h[((size_t)t * B_SZ + r0 + xrow) * D_DIM + xc * 16];
                xa = *reinterpret_cast<const uint4*>(xp);
                xb = *reinterpret_cast<const uint4*>(xp + 8);
            }

            if (tid == 0) {
                while (__hip_atomic_fetch_add(gctr, 0u, __ATOMIC_RELAXED,
                                              __HIP_MEMORY_SCOPE_AGENT) < 8u * (unsigned)t)
                    __builtin_amdgcn_s_sleep(1);
            }
            __syncthreads();
            asm volatile("" ::: "memory");

            ull hv[8];
            const ull* hrow = reinterpret_cast<const ull*>(&hb_r[(size_t)(r0 + srow) * E_DIM]);
            #pragma unroll
            for (int q = 0; q < 4; ++q) {
                const int c = seg + 16 * q;
                hv[2*q]   = __hip_atomic_load(hrow + 2*c,     __ATOMIC_RELAXED, __HIP_MEMORY_SCOPE_SYSTEM);
                hv[2*q+1] = __hip_atomic_load(hrow + 2*c + 1, __ATOMIC_RELAXED, __HIP_MEMORY_SCOPE_SYSTEM);
            }
            #pragma unroll
            for (int q = 0; q < 4; ++q) {
                const int c = seg + 16 * q;
                uint4 pk;
                __builtin_memcpy(&pk, &hv[2*q], 16);
                *reinterpret_cast<uint4*>(hAb + rswz(srow, 16 * c)) = pk;
            }
            if (tid < 64) {
                *reinterpret_cast<uint4*>(hAb + rswz(xrow, 1024 + 32 * xc))      = xa;
                *reinterpret_cast<uint4*>(hAb + rswz(xrow, 1024 + 32 * xc + 16)) = xb;
            }
            __syncthreads();

            if (tl == 0) {   // hse[0] = bf16(h(t0)) from regs
                #pragma unroll
                for (int q = 0; q < 4; ++q) {
                    const int c = seg + 16 * q;
                    unsigned short o[8];
                    #pragma unroll
                    for (int j = 0; j < 4; ++j) o[j]     = f2bf(h2f((unsigned short)(hv[2*q]   >> (16 * j))));
                    #pragma unroll
                    for (int j = 0; j < 4; ++j) o[4 + j] = f2bf(h2f((unsigned short)(hv[2*q+1] >> (16 * j))));
                    uint4 pk;
                    __builtin_memcpy(&pk, o, 16);
                    *reinterpret_cast<uint4*>(&hse[(size_t)(r0 + srow) * E_DIM + 8 * c]) = pk;
                }
            }

            f32x4 accA = (f32x4){0.f, 0.f, 0.f, 0.f};
            f32x4 accB = (f32x4){0.f, 0.f, 0.f, 0.f};
            #pragma unroll
            for (int ks = 0; ks < 18; ++ks) {
                half8 a = *reinterpret_cast<const half8*>(hAb + rswz(arow, ks * 64 + kq * 16));
                half8 b = *reinterpret_cast<const half8*>(Wlb + rswz(wave * 16 + arow, ks * 64 + kq * 16));
                if (ks & 1) accB = __builtin_amdgcn_mfma_f32_16x16x32_f16(a, b, accB, 0, 0, 0);
                else        accA = __builtin_amdgcn_mfma_f32_16x16x32_f16(a, b, accA, 0, 0, 0);
            }
            f32x4 acc = accA + accB;

            // epilogue: system-store h(t+1) slice; keep values in regs for hse write
            const int ncol = n0 + wave * 16 + arow;
            float hsv[8];
            #pragma unroll
            for (int nt = 0; nt < 2; ++nt)
                #pragma unroll
                for (int i = 0; i < 4; ++i) {
                    const int row = r0 + kq * 4 + i;
                    float hvf = fast_tanh(acc[nt * 4 + i < 4 ? i : i]);   // placeholder fixed below
                    (void)hvf;
                }
            // (explicit two-acc epilogue; acc holds nt in acc[i]? No: acc is per-nt pair)
            // -- real epilogue --
            {
                #pragma unroll
                for (int i = 0; i < 4; ++i) {
                    const int row = r0 + kq * 4 + i;
                    float h0 = fast_tanh(acc[i]);            // nt = 0 cols handled below
                    (void)row; (void)h0;
                }
            }
            // NOTE: single-ntile layout — wave covers 16 cols (ncol), acc[i] maps rows.
            #pragma unroll
            for (int i = 0; i < 4; ++i) {
                const int row = r0 + kq * 4 + i;
                float hvf = fast_tanh(acc[i]);
                hsv[i] = hvf;
                __hip_atomic_store(&hb_w[(size_t)row * E_DIM + ncol], f2h(hvf),
                                   __ATOMIC_RELAXED, __HIP_MEMORY_SCOPE_SYSTEM);
            }

            asm volatile("s_waitcnt vmcnt(0)" ::: "memory");
            __syncthreads();
            if (tid == 0)
                __hip_atomic_fetch_add(gctr, 1u, __ATOMIC_RELAXED, __HIP_MEMORY_SCOPE_AGENT);

            // hse writes AFTER the flag (not on the barrier critical path)
            if (tl + 1 < tce) {
                #pragma unroll
                for (int i = 0; i < 4; ++i) {
                    const int row = r0 + kq * 4 + i;
                    hse[((size_t)(tl + 1) * B_SZ + row) * E_DIM + ncol] = f2bf(hsv[i]);
                }
            }
        }
    } else {
        // ================= FLOW part (R9 verified structure) =================
        if (tcf <= 0) return;
        const int fbid = (int)blockIdx.x - ebn;
        const int tt   = fbid >> 4;
        const int bt   = fbid & 15;

        unsigned short* abf   = reinterpret_cast<unsigned short*>(smem);          // [32][SA]
        unsigned short* hidbf = abf + 32 * SA;                                    // [32][SH]
        float* zf    = reinterpret_cast<float*>(hidbf + 32 * SH);                 // [32][64]
        float* llacc = zf + 32 * 64;
        float* llb   = llacc + 32;
        float* stf   = reinterpret_cast<float*>(hidbf);                           // [32][SF] alias

        if (tid < 16) llb[tid] = 0.f;

        const int r8 = tid >> 3;
        const int c8 = tid & 7;

        for (int s = 0; s < 8; ++s) {
            const int trow = tt * 16 + 2 * s + (r8 >> 4);
            const int brow = bt * 16 + (r8 & 15);
            {
                const float* xp = &x_seq[((size_t)(t0f + trow) * B_SZ + brow) * D_DIM + c8 * 8];
                float4 v0 = *reinterpret_cast<const float4*>(xp);
                float4 v1 = *reinterpret_cast<const float4*>(xp + 4);
                *reinterpret_cast<float4*>(&zf[r8 * 64 + c8 * 8])     = v0;
                *reinterpret_cast<float4*>(&zf[r8 * 64 + c8 * 8 + 4]) = v1;
                const unsigned short* hp = &hsf[((size_t)trow * B_SZ + brow) * E_DIM + c8 * 64];
                unsigned short* ap = &abf[r8 * SA + 32 + c8 * 64];
                #pragma unroll
                for (int q = 0; q < 8; ++q)
                    *reinterpret_cast<uint4*>(ap + q * 8) = *reinterpret_cast<const uint4*>(hp + q * 8);
            }
            if (tid < 32) llacc[tid] = 0.f;
            __syncthreads();

            for (int stage = 0; stage < 8; ++stage) {
                const int l = 3 - (stage >> 1);
                const int side = stage & 1;
                const int ls = l * 2 + side;
                {
                    #pragma unroll
                    for (int q = 0; q < 4; ++q) {
                        int k = c8 * 4 + q;
                        int d = side ? k : (32 + k);
                        abf[r8 * SA + k] = f2bf(zf[r8 * 64 + d]);
                    }
                }
                __syncthreads();

                const unsigned short* wbase =
                    W_inF + ((size_t)(ls * 16 + wave * 4) * 17) * 512 + lane * 8;
                f32x4 acc[2][4];
                #pragma unroll
                for (int mt = 0; mt < 2; ++mt)
                    #pragma unroll
                    for (int nt = 0; nt < 4; ++nt)
                        acc[mt][nt] = (f32x4){0.f, 0.f, 0.f, 0.f};
                const int aoff = (lane & 15) * SA + 8 * (lane >> 4);
                short8 bb[6][4];
                #pragma unroll
                for (int p = 0; p < 6; ++p)
                    #pragma unroll
                    for (int nt = 0; nt < 4; ++nt)
                        bb[p][nt] = *reinterpret_cast<const short8*>(wbase + (size_t)nt * 8704 + p * 512);
                #pragma unroll
                for (int ks = 0; ks < 17; ++ks) {
                    const int k0 = ks * 32;
                    short8 a0 = *reinterpret_cast<const short8*>(&abf[aoff + k0]);
                    short8 a1 = *reinterpret_cast<const short8*>(&abf[16 * SA + aoff + k0]);
                    #pragma unroll
                    for (int nt = 0; nt < 4; ++nt) {
                        acc[0][nt] = __builtin_amdgcn_mfma_f32_16x16x32_bf16(a0, bb[ks % 6][nt], acc[0][nt], 0, 0, 0);
                        acc[1][nt] = __builtin_amdgcn_mfma_f32_16x16x32_bf16(a1, bb[ks % 6][nt], acc[1][nt], 0, 0, 0);
                    }
                    if (ks + 6 < 17) {
                        #pragma unroll
                        for (int nt = 0; nt < 4; ++nt)
                            bb[ks % 6][nt] = *reinterpret_cast<const short8*>(
                                wbase + (size_t)nt * 8704 + (ks + 6) * 512);
                    }
                }
                #pragma unroll
                for (int mt = 0; mt < 2; ++mt)
                    #pragma unroll
                    for (int nt = 0; nt < 4; ++nt) {
                        const int n = wave * 64 + nt * 16 + (lane & 15);
                        const float bias = b_in[l * H_DIM + n];
                        #pragma unroll
                        for (int i = 0; i < 4; ++i) {
                            const int row = mt * 16 + (lane >> 4) * 4 + i;
                            hidbf[row * SH + n] = f2bf(fast_tanh(acc[mt][nt][i] + bias));
                        }
                    }
                __syncthreads();

                const unsigned short* wstb =
                    W_stF + ((size_t)(ls * 4 + wave) * 8) * 512 + lane * 8;
                f32x4 acc2[2];
                acc2[0] = (f32x4){0.f,0.f,0.f,0.f};
                acc2[1] = (f32x4){0.f,0.f,0.f,0.f};
                const int hoff = (lane & 15) * SH + 8 * (lane >> 4);
                const int nst  = wave * 16 + (lane & 15);
                short8 bs0 = *reinterpret_cast<const short8*>(wstb);
                #pragma unroll
                for (int ks = 0; ks < 8; ++ks) {
                    short8 bcur = bs0;
                    if (ks + 1 < 8) bs0 = *reinterpret_cast<const short8*>(wstb + (ks + 1) * 512);
                    const int k0 = ks * 32;
                    short8 a0 = *reinterpret_cast<const short8*>(&hidbf[hoff + k0]);
                    short8 a1 = *reinterpret_cast<const short8*>(&hidbf[16 * SH + hoff + k0]);
                    acc2[0] = __builtin_amdgcn_mfma_f32_16x16x32_bf16(a0, bcur, acc2[0], 0, 0, 0);
                    acc2[1] = __builtin_amdgcn_mfma_f32_16x16x32_bf16(a1, bcur, acc2[1], 0, 0, 0);
                }
                __syncthreads();
                {
                    const int j = nst & 31;
                    const int d = side ? (32 + j) : j;
                    const bool is_s = (nst < 32);
                    const float bias = is_s ? b_s[l * D_DIM + d] : b_t[l * D_DIM + d];
                    const float rs = rescale_w[d];
                    #pragma unroll
                    for (int mt = 0; mt < 2; ++mt)
                        #pragma unroll
                        for (int i = 0; i < 4; ++i) {
                            const int row = mt * 16 + (lane >> 4) * 4 + i;
                            const float v = acc2[mt][i] + bias;
                            stf[row * SF + nst] = is_s ? (fast_tanh(v) * rs) : v;
                        }
                }
                __syncthreads();
                {
                    float p = 0.f;
                    #pragma unroll
                    for (int q = 0; q < 4; ++q) {
                        const int j = c8 * 4 + q;
                        const int d = side ? (32 + j) : j;
                        const float sv = stf[r8 * SF + j];
                        const float iv = stf[r8 * SF + 32 + j];
                        zf[r8 * 64 + d] = (zf[r8 * 64 + d] - iv) * __expf(-sv);
                        p += sv;
                    }
                    p += __shfl_xor(p, 1);
                    p += __shfl_xor(p, 2);
                    p += __shfl_xor(p, 4);
                    if (c8 == 0) llacc[r8] -= p;
                }
                __syncthreads();
            } // stage

            {
                float zs = 0.f;
                #pragma unroll
                for (int q = 0; q < 8; ++q) {
                    float z = zf[r8 * 64 + c8 * 8 + q];
                    zs += z * z;
                }
                zs += __shfl_xor(zs, 1);
                zs += __shfl_xor(zs, 2);
                zs += __shfl_xor(zs, 4);
                if (c8 == 0) {
                    float ll = llacc[r8] - 0.5f * zs - 58.812066125f;
                    llacc[r8] = ((t0f + trow) < seq_len[brow]) ? ll : 0.f;
                }
            }
            __syncthreads();
            if (tid < 16) llb[tid] += llacc[tid] + llacc[16 + tid];
            __syncthreads();
        } // subtiles

        if (tid < 16)
            ll_part[((t0f >> 4) + tt) * B_SZ + bt * 16 + tid] = llb[tid];
    }
}

__global__ void reduce_kernel(const float* __restrict__ ll_part, float* __restrict__ out) {
    int b = threadIdx.x;
    float s = 0.f;
    #pragma unroll
    for (int tt = 0; tt < T_LEN / 16; ++tt) s += ll_part[tt * B_SZ + b];
    out[b] = s;
}

extern "C" void kernel_launch(void* const* d_in, const int* in_sizes, int n_in,
                              void* d_out, int out_size, void* d_ws, size_t ws_size,
                              hipStream_t stream) {
    const float* x_seq   = (const float*)d_in[0];
    const int*   seqlen  = (const int*)d_in[1];
    const float* W_in    = (const float*)d_in[3];
    const float* b_in    = (const float*)d_in[4];
    const float* W_s     = (const float*)d_in[5];
    const float* b_s     = (const float*)d_in[6];
    const float* W_t     = (const float*)d_in[7];
    const float* b_t     = (const float*)d_in[8];
    const float* rescale = (const float*)d_in[9];
    const float* W_res   = (const float*)d_in[10];
    const float* W_inp   = (const float*)d_in[11];

    char* ws = (char*)d_ws;
    size_t off = 0;
    unsigned short* W_inF  = (unsigned short*)(ws + off); off += (size_t)8 * 16 * 17 * 64 * 8 * 2;
    unsigned short* W_stF  = (unsigned short*)(ws + off); off += (size_t)8 * 4 * 8 * 64 * 8 * 2;
    unsigned short* W_pack = (unsigned short*)(ws + off); off += (size_t)E_DIM * 576 * 2;
    unsigned short* x_h    = (unsigned short*)(ws + off); off += (size_t)T_LEN * B_SZ * D_DIM * 2;
    float* ll_part = (float*)(ws + off); off += (size_t)(T_LEN / 16) * B_SZ * 4;
    unsigned short* h_buf  = (unsigned short*)(ws + off); off += (size_t)2 * B_SZ * E_DIM * 2;
    unsigned int* ctr = (unsigned int*)(ws + off); off += (size_t)16 * 32 * 4;
    unsigned short* hs_base = (unsigned short*)(ws + off);

    const size_t per_t = (size_t)B_SZ * E_DIM * 2;
    size_t rem = (ws_size > off) ? (ws_size - off) : 0;

    hipMemsetAsync(h_buf, 0, (size_t)2 * B_SZ * E_DIM * 2, stream);
    hipMemsetAsync(ctr, 0, (size_t)16 * 32 * 4, stream);
    prep_kernel<<<2048, 256, 0, stream>>>(W_in, W_s, W_t, W_res, W_inp, x_seq,
                                          W_inF, W_stF, W_pack, x_h);

    long long tpd = (long long)(rem / (2 * per_t));   // pipelined (double-buffer) chunk
    int tcp = (int)((tpd > 128) ? 128 : tpd);
    tcp &= ~15;

    if (tcp >= 16) {
        // ---- pipelined: fused(esn chunk c || flow chunk c-1), double-buffered hs ----
        unsigned short* hs0 = hs_base;
        unsigned short* hs1 = hs_base + (size_t)tcp * B_SZ * E_DIM;
        int c = 0, pt0 = 0, pcur = 0;
        for (int t0 = 0; t0 < T_LEN; t0 += tcp, ++c) {
            int cur = T_LEN - t0; if (cur > tcp) cur = tcp;
            unsigned short* hse = (c & 1) ? hs1 : hs0;
            unsigned short* hsf = (c & 1) ? hs0 : hs1;
            fused_kernel<<<128 + pcur, 256, ESN_LDS, stream>>>(
                x_h, W_pack, hse, h_buf, ctr, t0, cur,
                x_seq, hsf, W_inF, W_stF, b_in, b_s, b_t, rescale, seqlen, ll_part,
                pt0, pcur);
            pt0 = t0; pcur = cur;
        }
        unsigned short* hsl = ((c - 1) & 1) ? hs1 : hs0;   // last chunk's buffer
        fused_kernel<<<pcur, 256, FLOW_LDS, stream>>>(
            x_h, W_pack, hs0, h_buf, ctr, 0, 0,
            x_seq, hsl, W_inF, W_stF, b_in, b_s, b_t, rescale, seqlen, ll_part,
            pt0, pcur);
    } else {
        // ---- sequential fallback (R9 schedule), single hs buffer ----
        long long tsd = (long long)(rem / per_t);
        int tcs = (int)((tsd > T_LEN) ? T_LEN : tsd);
        tcs &= ~15;
        if (tcs < 16) tcs = 16;
        for (int t0 = 0; t0 < T_LEN; t0 += tcs) {
            int cur = T_LEN - t0; if (cur > tcs) cur = tcs;
            fused_kernel<<<128, 256, ESN_LDS, stream>>>(
                x_h, W_pack, hs_base, h_buf, ctr, t0, cur,
                x_seq, hs_base, W_inF, W_stF, b_in, b_s, b_t, rescale, seqlen, ll_part,
                0, 0);
            fused_kernel<<<cur, 256, FLOW_LDS, stream>>>(
                x_h, W_pack, hs_base, h_buf, ctr, 0, 0,
                x_seq, hs_base, W_inF, W_stF, b_in, b_s, b_t, rescale, seqlen, ll_part,
                t0, cur);
        }
    }
    reduce_kernel<<<1, B_SZ, 0, stream>>>(ll_part, (float*)d_out);
}